// Round 6
// baseline (36.758 us; speedup 1.0000x reference)
//
#include <hip/hip_runtime.h>

#define NB 8
#define NP 131072
#define NM 16
#define THRESH 0.5f
#define BLK 256
#define PPT 4                    // priors per thread
#define PPB (BLK * PPT)          // 1024 priors per block
#define BPB (NP / PPB)           // 128 blocks per batch
#define NPAIR (NB * NM)          // 128 (b,m) pairs
#define NBLOCKS (NB * BPB)       // 1024

typedef unsigned long long u64;
typedef unsigned int u32;

// ---------- DPP wave-64 reductions (no DS, no SALU round-trips) ----------
// row_shr 1,2,4,8 then row_bcast:15, row_bcast:31; lane 63 holds the result.
// old=0 fill is harmless: sum adds 0; u64-key max: 0 never wins (real keys != 0).

template <int CTRL>
__device__ __forceinline__ float dppmv(float x) {
    return __int_as_float(__builtin_amdgcn_update_dpp(
        0, __float_as_int(x), CTRL, 0xf, 0xf, false));
}

template <int CTRL>
__device__ __forceinline__ u64 dppu64(u64 k) {
    u32 lo = (u32)__builtin_amdgcn_update_dpp(0, (int)(u32)k,        CTRL, 0xf, 0xf, false);
    u32 hi = (u32)__builtin_amdgcn_update_dpp(0, (int)(u32)(k >> 32), CTRL, 0xf, 0xf, false);
    return ((u64)hi << 32) | lo;
}

__device__ __forceinline__ u64 wave_maxkey63(u64 k) {
    u64 o;
    o = dppu64<0x111>(k); k = (o > k) ? o : k;
    o = dppu64<0x112>(k); k = (o > k) ? o : k;
    o = dppu64<0x114>(k); k = (o > k) ? o : k;
    o = dppu64<0x118>(k); k = (o > k) ? o : k;
    o = dppu64<0x142>(k); k = (o > k) ? o : k;
    o = dppu64<0x143>(k); k = (o > k) ? o : k;
    return k;                                    // valid in lane 63
}

__device__ __forceinline__ float wave_sum63(float x) {
    x += dppmv<0x111>(x);
    x += dppmv<0x112>(x);
    x += dppmv<0x114>(x);
    x += dppmv<0x118>(x);
    x += dppmv<0x142>(x);
    x += dppmv<0x143>(x);
    return x;                                    // valid in lane 63
}

// ---------- shared math (identical formulas in BOTH kernels for consistency) ----------

__device__ __forceinline__ float iou_term(float inter, float va, float vb) {
    return (inter > 0.0f) ? inter * __builtin_amdgcn_rcpf(va + vb - inter) : 0.0f;
}

__device__ __forceinline__ float focal_term(float x, bool pos) {
    float t = __expf(-fabsf(x));                 // e^{-|x|}
    float r = __builtin_amdgcn_rcpf(1.0f + t);   // 1/(1+t)
    float L = __logf(1.0f + t);                  // log1p(e^{-|x|})
    float ce = (pos ? fmaxf(-x, 0.0f) : fmaxf(x, 0.0f)) + L;   // softplus
    float omp = (pos == (x >= 0.0f)) ? t * r : r;              // 1 - pt
    float w = pos ? 0.25f : 0.75f;
    return w * omp * omp * ce;
}

__device__ __forceinline__ float l1_enc(const float* lp,
                                        const float blo[3], const float bhi[3],
                                        const float pc[3], const float ps[3]) {
    float s = 0.0f;
#pragma unroll
    for (int k = 0; k < 3; ++k) {
        float gc = (blo[k] + bhi[k]) / 2.0f;
        float gs = bhi[k] - blo[k];
        float e  = (gc - pc[k]) / (ps[k] / 10.0f);
        float e2 = __logf(gs / ps[k]) * 5.0f;
        s += fabsf(lp[k]     - e);
        s += fabsf(lp[3 + k] - e2);
    }
    return s;
}

__device__ __forceinline__ u32 decode_p(u64 k) { return ~(u32)(k & 0xFFFFFFFFull); }

// ---------- kernel A: match + pre-override loss partials ----------
// boxes/labels are wave-uniform -> scalar loads; no LDS staging.

__global__ __launch_bounds__(BLK) void match_loss_kernel(
        const float* __restrict__ locs, const float* __restrict__ scores,
        const float* __restrict__ boxes, const int* __restrict__ labels,
        const float* __restrict__ priors,
        u64* __restrict__ keys_out,              // [NPAIR][BPB], fully written
        float4* __restrict__ part) {             // [NBLOCKS] {focal, loc, npos, 0}
    __shared__ u64   s_wkey[4][NM];
    __shared__ float s_wred[4][3];

    const int tid  = threadIdx.x;
    const int b    = blockIdx.y;
    const int lane = tid & 63, wave = tid >> 6;
    const int p0   = blockIdx.x * PPB + PPT * tid;   // multiple of 4

    // uniform label mask (scalar ops)
    int lab_mask = 0;
#pragma unroll
    for (int m = 0; m < NM; ++m)
        lab_mask |= (labels[b * NM + m] > 0) ? (1 << m) : 0;

    // 4 priors: 6 aligned float4 loads (offset 24*p0 bytes, p0 % 4 == 0)
    const float4* pr4 = reinterpret_cast<const float4*>(priors);
    const size_t f4b = (size_t)(p0 / 2) * 3;
    float4 q0 = pr4[f4b + 0], q1 = pr4[f4b + 1], q2 = pr4[f4b + 2];
    float4 q3 = pr4[f4b + 3], q4 = pr4[f4b + 4], q5 = pr4[f4b + 5];
    float pl[PPT][3], ph[PPT][3], vb[PPT];
    {
        const float qf[24] = {q0.x,q0.y,q0.z,q0.w, q1.x,q1.y,q1.z,q1.w,
                              q2.x,q2.y,q2.z,q2.w, q3.x,q3.y,q3.z,q3.w,
                              q4.x,q4.y,q4.z,q4.w, q5.x,q5.y,q5.z,q5.w};
#pragma unroll
        for (int j = 0; j < PPT; ++j) {
#pragma unroll
            for (int k = 0; k < 3; ++k) {
                float c = qf[6 * j + k], s = qf[6 * j + 3 + k];
                pl[j][k] = c - s / 2.0f;             // mirror reference op order
                ph[j][k] = c + s / 2.0f;
            }
            vb[j] = (ph[j][0] - pl[j][0]) * (ph[j][1] - pl[j][1]) * (ph[j][2] - pl[j][2]);
        }
    }

    float best[PPT]; int bm[PPT];
#pragma unroll
    for (int j = 0; j < PPT; ++j) { best[j] = -1.0f; bm[j] = 0; }

#pragma unroll
    for (int m = 0; m < NM; ++m) {
        // wave-uniform box -> s_load + SGPR operands
        const float* bx = &boxes[(b * NM + m) * 6];
        const float bl0 = bx[0], bl1 = bx[1], bl2 = bx[2];
        const float bh0 = bx[3], bh1 = bx[4], bh2 = bx[5];
        const float va = (bh0 - bl0) * (bh1 - bl1) * (bh2 - bl2);

        u64 k = 0;
#pragma unroll
        for (int j = 0; j < PPT; ++j) {          // ascending p; > keeps lowest p on tie
            float d0 = fminf(bh0, ph[j][0]) - fmaxf(bl0, pl[j][0]);
            float d1 = fminf(bh1, ph[j][1]) - fmaxf(bl1, pl[j][1]);
            float d2 = fminf(bh2, ph[j][2]) - fmaxf(bl2, pl[j][2]);
            float inter = fmaxf(d0, 0.0f) * fmaxf(d1, 0.0f) * fmaxf(d2, 0.0f);
            float iou = iou_term(inter, va, vb[j]);
            if (iou > best[j]) { best[j] = iou; bm[j] = m; }   // strict > = first max
            u64 kj = ((u64)__float_as_uint(iou) << 32) | (u32)~(u32)(p0 + j);
            k = (kj > k) ? kj : k;
        }
        // full-wave packed max (pure VALU; overlaps next m's IoU math)
        k = wave_maxkey63(k);
        if (lane == 63) s_wkey[wave][m] = k;
    }

    // pre-override losses for the 4 priors
    const float4* sc4 = reinterpret_cast<const float4*>(scores);
    const size_t scb = ((size_t)b * NP + p0) >> 1;
    float4 sA = sc4[scb], sB = sc4[scb + 1];
    const float xs[PPT] = {sA.y, sA.w, sB.y, sB.w};

    float f = 0.0f, l = 0.0f, n = 0.0f;
#pragma unroll
    for (int j = 0; j < PPT; ++j) {
        const bool pos = (best[j] >= THRESH) && ((lab_mask >> bm[j]) & 1);
        f += focal_term(xs[j], pos);
        if (pos) {                               // rare path: exec-masked reloads
            const int p = p0 + j;
            float pc[3], ps[3], blo[3], bhi[3];
#pragma unroll
            for (int k = 0; k < 3; ++k) {
                pc[k]  = priors[p * 6 + k];
                ps[k]  = priors[p * 6 + 3 + k];
                blo[k] = boxes[(b * NM + bm[j]) * 6 + k];
                bhi[k] = boxes[(b * NM + bm[j]) * 6 + 3 + k];
            }
            l += l1_enc(&locs[((size_t)b * NP + p) * 6], blo, bhi, pc, ps);
            n += 1.0f;
        }
    }

    f = wave_sum63(f); l = wave_sum63(l); n = wave_sum63(n);
    if (lane == 63) { s_wred[wave][0] = f; s_wred[wave][1] = l; s_wred[wave][2] = n; }
    __syncthreads();

    if (tid < NM) {
        u64 k = s_wkey[0][tid];
#pragma unroll
        for (int w = 1; w < 4; ++w) k = (s_wkey[w][tid] > k) ? s_wkey[w][tid] : k;
        keys_out[(size_t)(b * NM + tid) * BPB + blockIdx.x] = k;
    }
    if (tid == 0) {
        part[b * BPB + blockIdx.x] =
            make_float4(s_wred[0][0] + s_wred[1][0] + s_wred[2][0] + s_wred[3][0],
                        s_wred[0][1] + s_wred[1][1] + s_wred[2][1] + s_wred[3][1],
                        s_wred[0][2] + s_wred[1][2] + s_wred[2][2] + s_wred[3][2],
                        0.0f);
    }
}

// ---------- kernel B: key reduce + partial reduce + override fixups + finalize ----------

__global__ __launch_bounds__(1024) void finalize_kernel(
        const float* __restrict__ locs, const float* __restrict__ scores,
        const float* __restrict__ boxes, const int* __restrict__ labels,
        const float* __restrict__ priors, const u64* __restrict__ keys_in,
        const float4* __restrict__ part, float* __restrict__ out) {
    __shared__ u64   s_key[NPAIR];
    __shared__ float s_red[16][3];
    __shared__ float s_fix[16][3];
    const int t = threadIdx.x, lane = t & 63, wave = t >> 6;   // 16 waves

    // 1) reduce per-block loss partials
    float f = 0.0f, l = 0.0f, n = 0.0f;
    for (int i = t; i < NBLOCKS; i += 1024) {
        float4 v = part[i]; f += v.x; l += v.y; n += v.z;
    }
    f = wave_sum63(f); l = wave_sum63(l); n = wave_sum63(n);
    if (lane == 63) { s_red[wave][0] = f; s_red[wave][1] = l; s_red[wave][2] = n; }

    // 2) global key max per (b,m): one wave per 8 pairs
#pragma unroll
    for (int i = 0; i < 8; ++i) {
        const int pair = wave * 8 + i;
        const u64* kp = keys_in + (size_t)pair * BPB;
        u64 k = 0;
#pragma unroll
        for (int j = 0; j < BPB / 64; ++j) {     // 2 coalesced loads per lane
            u64 v = kp[j * 64 + lane];
            k = (v > k) ? v : k;
        }
#pragma unroll
        for (int off = 32; off > 0; off >>= 1) {
            u64 o = __shfl_down(k, off);
            k = (o > k) ? o : k;
        }
        if (lane == 0) s_key[pair] = k;
    }
    __syncthreads();

    // 3) per-(b,m) override fixup
    float df = 0.0f, dl = 0.0f, dn = 0.0f;
    if (t < NPAIR) {
        const int b = t / NM, m = t % NM;
        const u32 pstar = decode_p(s_key[t]);
        bool skip = false;                        // duplicate prior: last m wins
        for (int mm = m + 1; mm < NM; ++mm)
            skip |= (decode_p(s_key[b * NM + mm]) == pstar);
        if (!skip) {
            const int p = (int)pstar;
            float pc[3], ps[3], pl[3], ph[3];
#pragma unroll
            for (int k = 0; k < 3; ++k) { pc[k] = priors[p * 6 + k]; ps[k] = priors[p * 6 + 3 + k]; }
#pragma unroll
            for (int k = 0; k < 3; ++k) { pl[k] = pc[k] - ps[k] / 2.0f; ph[k] = pc[k] + ps[k] / 2.0f; }
            const float vb = (ph[0] - pl[0]) * (ph[1] - pl[1]) * (ph[2] - pl[2]);

            // recompute this prior's original best match (bit-identical math to A)
            float best = -1.0f; int bestm = 0;
            for (int mm = 0; mm < NM; ++mm) {
                const float* bx = &boxes[(b * NM + mm) * 6];
                float d0 = fminf(bx[3], ph[0]) - fmaxf(bx[0], pl[0]);
                float d1 = fminf(bx[4], ph[1]) - fmaxf(bx[1], pl[1]);
                float d2 = fminf(bx[5], ph[2]) - fmaxf(bx[2], pl[2]);
                float inter = fmaxf(d0, 0.0f) * fmaxf(d1, 0.0f) * fmaxf(d2, 0.0f);
                float va = (bx[3] - bx[0]) * (bx[4] - bx[1]) * (bx[5] - bx[2]);
                float iou = iou_term(inter, va, vb);
                if (iou > best) { best = iou; bestm = mm; }
            }
            const bool old_pos = (best >= THRESH) && (labels[b * NM + bestm] > 0);
            const bool new_pos = (labels[b * NM + m] > 0);   // overlap forced to 1.0

            const float x = scores[((size_t)b * NP + p) * 2 + 1];
            df = focal_term(x, new_pos) - focal_term(x, old_pos);
            dn = (new_pos ? 1.0f : 0.0f) - (old_pos ? 1.0f : 0.0f);

            const float* lp = &locs[((size_t)b * NP + p) * 6];
            if (new_pos) {
                const float* bx = &boxes[(b * NM + m) * 6];
                float blo[3] = {bx[0], bx[1], bx[2]}, bhi[3] = {bx[3], bx[4], bx[5]};
                dl += l1_enc(lp, blo, bhi, pc, ps);
            }
            if (old_pos) {
                const float* bx = &boxes[(b * NM + bestm) * 6];
                float blo[3] = {bx[0], bx[1], bx[2]}, bhi[3] = {bx[3], bx[4], bx[5]};
                dl -= l1_enc(lp, blo, bhi, pc, ps);
            }
        }
    }
    df = wave_sum63(df); dl = wave_sum63(dl); dn = wave_sum63(dn);
    if (lane == 63) { s_fix[wave][0] = df; s_fix[wave][1] = dl; s_fix[wave][2] = dn; }
    __syncthreads();

    // 4) finalize (single thread, fixed order)
    if (t == 0) {
        float tf = 0.0f, tl = 0.0f, tn = 0.0f;
        for (int w = 0; w < 16; ++w) {
            tf += s_red[w][0] + s_fix[w][0];
            tl += s_red[w][1] + s_fix[w][1];
            tn += s_red[w][2] + s_fix[w][2];
        }
        out[0] = tf / (float)(NB * NP);                                   // conf_loss
        out[1] = (tn > 0.5f) ? tl / fmaxf(tn * 6.0f, 1.0f) : 0.0f;        // loc_loss
    }
}

// ---------- launch (2 dispatches, no memset) ----------

extern "C" void kernel_launch(void* const* d_in, const int* in_sizes, int n_in,
                              void* d_out, int out_size, void* d_ws, size_t ws_size,
                              hipStream_t stream) {
    const float* locs   = (const float*)d_in[0];
    const float* scores = (const float*)d_in[1];
    const float* boxes  = (const float*)d_in[2];
    const int*   labels = (const int*)d_in[3];
    const float* priors = (const float*)d_in[4];
    float* out = (float*)d_out;

    u64*    keys = (u64*)d_ws;                                        // 128 KB
    float4* part = (float4*)((char*)d_ws + (size_t)NPAIR * BPB * 8);  // 16 KB

    dim3 grid(BPB, NB);
    match_loss_kernel<<<grid, BLK, 0, stream>>>(locs, scores, boxes, labels, priors,
                                                keys, part);
    finalize_kernel<<<1, 1024, 0, stream>>>(locs, scores, boxes, labels, priors, keys,
                                            part, out);
}